// Round 6
// baseline (1239.900 us; speedup 1.0000x reference)
//
#include <hip/hip_runtime.h>
#include <float.h>
#include <stdint.h>

#define IN_DIM 1433
#define HID 16
#define OUTD 7

// gemm1: 128 rows/block, K-tiles of 32, 4-deep LDS ring, counted-vmcnt pipeline
#define BRW 128
#define KCW 32
#define DEPTH 4
#define NTW ((IN_DIM + KCW - 1) / KCW)     // 45
#define KLASTW (IN_DIM - (NTW - 1) * KCW)  // 25
#define WN (IN_DIM * HID)                  // 22928 floats of W1

#define AS1 __attribute__((address_space(1)))
#define AS3 __attribute__((address_space(3)))

// ---------------- GEMM1: xw1[N][16] = feat[N][1433] @ W1[1433][16] -------------
// 512 threads = 8 waves, 1 block/CU (157 KB LDS). W1 fully resident in LDS
// (broadcast reads). x tiles (128x32) staged via width-4 global_load_lds into a
// 4-buffer ring; raw s_barrier + counted s_waitcnt vmcnt(N) keeps 2-3 tiles
// (32-48 KB/CU) in flight continuously -- never drains to 0 in the main loop.
// Swizzle (both-sides, rule #21): slot s of row r holds global col s^(r&31);
// read col kk at slot kk^(r&31) -> 2 lanes/bank (free).
__global__ __launch_bounds__(512, 1) void gemm1_kernel(
    const float* __restrict__ feat, const float* __restrict__ W1,
    float* __restrict__ xw1, int N)
{
    __shared__ float xs[DEPTH][BRW * KCW];   // 4 * 16 KB
    __shared__ float wl[WN];                 // 91712 B
    const int t = threadIdx.x;
    const int lane = t & 63;
    const int w = t >> 6;                    // wave 0..7
    const int row0 = blockIdx.x * BRW;
    const long maxElem = (long)N * IN_DIM - 1;

    // ---- preload W1 into LDS (drained once by __syncthreads) ----
    for (int i0 = 0; i0 < WN; i0 += 512) {
        if (i0 + t < WN) {
            __builtin_amdgcn_global_load_lds(
                (const AS1 void*)(W1 + i0 + t),
                (AS3 void*)(wl + i0 + w * 64), 4, 0, 0);
        }
    }
    __syncthreads();   // vmcnt(0) drain + barrier: W resident, counters at 0

    const int r  = t & (BRW - 1);   // row owned for compute
    const int rx = r & 31;
    const int q  = t >> 7;          // 0..3, uniform per wave: dims 4q..4q+3
    float acc[4] = {0.f, 0.f, 0.f, 0.f};

    const int l5 = lane >> 5;       // which of the 2 rows per DMA instr
    const int c  = lane & 31;       // slot within row

    // stage one 128x32 tile: exactly 8 DMA instrs per wave (vmcnt-countable)
    auto stage = [&](int buf, int k0) {
#pragma unroll
        for (int i = 0; i < 8; ++i) {
            const int rr = w * 16 + i * 2 + l5;
            long elem = (long)(row0 + rr) * IN_DIM + k0 + (c ^ (rr & 31));
            if (elem > maxElem) elem = maxElem;   // tail clamp (rows >= N only)
            __builtin_amdgcn_global_load_lds(
                (const AS1 void*)(feat + elem),
                (AS3 void*)(&xs[buf][(w * 16 + i * 2) * KCW]), 4, 0, 0);
        }
    };

#define COMPUTE(buf, k0v, KMAX)                                          \
    {                                                                    \
        const float* xrow = &xs[buf][r * KCW];                           \
        const float* wb = wl + (size_t)(k0v) * HID + q * 4;              \
        _Pragma("unroll")                                                \
        for (int kk = 0; kk < (KMAX); ++kk) {                            \
            const float x = xrow[kk ^ rx];                               \
            const float4 wv = *(const float4*)(wb + kk * HID);           \
            acc[0] += x * wv.x; acc[1] += x * wv.y;                      \
            acc[2] += x * wv.z; acc[3] += x * wv.w;                      \
        }                                                                \
    }

#define WAITBAR(Nimm)                                                    \
    asm volatile("s_waitcnt vmcnt(" #Nimm ")" ::: "memory");             \
    __builtin_amdgcn_sched_barrier(0);                                   \
    __builtin_amdgcn_s_barrier();                                        \
    __builtin_amdgcn_sched_barrier(0);

    stage(0, 0);
    stage(1, KCW);
    stage(2, 2 * KCW);                       // 3 tiles (24 instrs/wave) in flight
    for (int it = 0; it < NTW - 3; ++it) {   // it = 0..41
        WAITBAR(16);                         // tile it resident; it+1,it+2 flying
        stage((it + 3) & (DEPTH - 1), (it + 3) * KCW);
        COMPUTE(it & (DEPTH - 1), it * KCW, KCW);
    }
    WAITBAR(16);                             // tile 42 resident (43,44 flying)
    COMPUTE((NTW - 3) & (DEPTH - 1), (NTW - 3) * KCW, KCW);
    WAITBAR(8);                              // tile 43 resident
    COMPUTE((NTW - 2) & (DEPTH - 1), (NTW - 2) * KCW, KCW);
    WAITBAR(0);                              // tile 44 resident
    COMPUTE((NTW - 1) & (DEPTH - 1), (NTW - 1) * KCW, KLASTW);
#undef COMPUTE
#undef WAITBAR

    const int grow = row0 + r;
    if (grow < N)
        *(float4*)(xw1 + (size_t)grow * HID + q * 4) =
            make_float4(acc[0], acc[1], acc[2], acc[3]);
}

// ---------------- CSR build: histogram -> scan -> counting-sort fill ----------
__global__ __launch_bounds__(256) void hist_kernel(
    const int* __restrict__ dst, int* __restrict__ cnt, int E)
{
    const int e = blockIdx.x * 256 + threadIdx.x;
    if (e < E) atomicAdd(&cnt[dst[e]], 1);
}

// block = 256 threads, 4 elems/thread -> 1024 per block
__global__ __launch_bounds__(256) void scan1_kernel(
    const int* __restrict__ cnt, int* __restrict__ offs,
    int* __restrict__ bsum, int N)
{
    __shared__ int lds[256];
    const int t = threadIdx.x, b = blockIdx.x;
    const int base = b * 1024 + t * 4;
    int c0 = 0, c1 = 0, c2 = 0, c3 = 0;
    if (base + 0 < N) c0 = cnt[base + 0];
    if (base + 1 < N) c1 = cnt[base + 1];
    if (base + 2 < N) c2 = cnt[base + 2];
    if (base + 3 < N) c3 = cnt[base + 3];
    const int s = c0 + c1 + c2 + c3;
    lds[t] = s;
    __syncthreads();
    for (int off = 1; off < 256; off <<= 1) {
        int v = (t >= off) ? lds[t - off] : 0;
        __syncthreads();
        lds[t] += v;
        __syncthreads();
    }
    const int excl = lds[t] - s;
    if (t == 255) bsum[b] = lds[255];
    int run = excl;
    if (base + 0 < N) { offs[base + 0] = run; run += c0; }
    if (base + 1 < N) { offs[base + 1] = run; run += c1; }
    if (base + 2 < N) { offs[base + 2] = run; run += c2; }
    if (base + 3 < N) { offs[base + 3] = run; run += c3; }
}

// single block: exclusive scan of up to 256 block sums
__global__ __launch_bounds__(256) void scan2_kernel(
    const int* __restrict__ bsum, int* __restrict__ bbase, int NB)
{
    __shared__ int lds[256];
    const int t = threadIdx.x;
    const int v = (t < NB) ? bsum[t] : 0;
    lds[t] = v;
    __syncthreads();
    for (int off = 1; off < 256; off <<= 1) {
        int u = (t >= off) ? lds[t - off] : 0;
        __syncthreads();
        lds[t] += u;
        __syncthreads();
    }
    bbase[t] = lds[t] - v;
}

__global__ __launch_bounds__(256) void scan3_kernel(
    int* __restrict__ offs, int* __restrict__ cursor,
    const int* __restrict__ bbase, int N, int E)
{
    const int t = threadIdx.x, b = blockIdx.x;
    const int add = bbase[b];
    const int base = b * 1024 + t * 4;
#pragma unroll
    for (int i = 0; i < 4; ++i) {
        const int idx = base + i;
        if (idx < N) {
            const int v = offs[idx] + add;
            offs[idx] = v;
            cursor[idx] = v;
        }
    }
    if (b == 0 && t == 0) offs[N] = E;
}

__global__ __launch_bounds__(256) void fill_kernel(
    const int* __restrict__ src, const int* __restrict__ dst,
    const float* __restrict__ a, int* __restrict__ cursor,
    uint2* __restrict__ pairs, int E)
{
    const int e = blockIdx.x * 256 + threadIdx.x;
    if (e >= E) return;
    const int d = dst[e];
    const int pos = atomicAdd(&cursor[d], 1);
    pairs[pos] = make_uint2((unsigned)src[e], __float_as_uint(a[e]));
}

// ------- gather1: agg = sum(a*xw1[src]) ; fused h=relu(agg+b1); xw2 = h@W2 ----
// one wave per dst row: 16 lanes (dims) x 4 edge groups
__global__ __launch_bounds__(256) void gather1_kernel(
    const uint2* __restrict__ pairs, const int* __restrict__ offs,
    const float* __restrict__ xw1, const float* __restrict__ b1,
    const float* __restrict__ W2, float* __restrict__ xw2, int N)
{
    __shared__ float w2s[HID * OUTD];
    const int t = threadIdx.x;
    if (t < HID * OUTD) w2s[t] = W2[t];
    __syncthreads();
    const int lane = t & 63;
    const int r = blockIdx.x * 4 + (t >> 6);
    if (r >= N) return;
    const int dim = lane & 15;
    const int grp = lane >> 4;
    const int start = offs[r], end = offs[r + 1];
    float acc0 = 0.f, acc1 = 0.f;
    int e = start + grp;
    for (; e + 4 < end; e += 8) {
        const uint2 p0 = pairs[e];
        const uint2 p1 = pairs[e + 4];
        acc0 += __uint_as_float(p0.y) * xw1[(long)p0.x * HID + dim];
        acc1 += __uint_as_float(p1.y) * xw1[(long)p1.x * HID + dim];
    }
    if (e < end) {
        const uint2 p0 = pairs[e];
        acc0 += __uint_as_float(p0.y) * xw1[(long)p0.x * HID + dim];
    }
    float acc = acc0 + acc1;
    acc += __shfl_xor(acc, 16);
    acc += __shfl_xor(acc, 32);
    const float h = fmaxf(acc + b1[dim], 0.f);
    float sacc = 0.f;
    const int c = (dim < OUTD) ? dim : 0;
#pragma unroll
    for (int j = 0; j < HID; ++j) {
        const float hj = __shfl(h, j);
        sacc += hj * w2s[j * OUTD + c];
    }
    if (lane < 8) xw2[(long)r * 8 + lane] = (lane < OUTD) ? sacc : 0.f;
}

// ------- gather2: o = sum(a*xw2[src]) + b2 ; fused log_softmax -> out ---------
__global__ __launch_bounds__(256) void gather2_kernel(
    const uint2* __restrict__ pairs, const int* __restrict__ offs,
    const float* __restrict__ xw2, const float* __restrict__ b2,
    float* __restrict__ out, int N)
{
    const int t = threadIdx.x;
    const int lane = t & 63;
    const int r = blockIdx.x * 4 + (t >> 6);
    if (r >= N) return;
    const int dim = lane & 7;
    const int grp = lane >> 3;
    const int start = offs[r], end = offs[r + 1];
    float acc0 = 0.f, acc1 = 0.f;
    int e = start + grp;
    for (; e + 8 < end; e += 16) {
        const uint2 p0 = pairs[e];
        const uint2 p1 = pairs[e + 8];
        acc0 += __uint_as_float(p0.y) * xw2[(long)p0.x * 8 + dim];
        acc1 += __uint_as_float(p1.y) * xw2[(long)p1.x * 8 + dim];
    }
    if (e < end) {
        const uint2 p0 = pairs[e];
        acc0 += __uint_as_float(p0.y) * xw2[(long)p0.x * 8 + dim];
    }
    float acc = acc0 + acc1;
    acc += __shfl_xor(acc, 8);
    acc += __shfl_xor(acc, 16);
    acc += __shfl_xor(acc, 32);
    float x = (dim < OUTD) ? (acc + b2[dim]) : -FLT_MAX;
    float m = x;
    m = fmaxf(m, __shfl_xor(m, 1));
    m = fmaxf(m, __shfl_xor(m, 2));
    m = fmaxf(m, __shfl_xor(m, 4));
    const float ev = (dim < OUTD) ? expf(x - m) : 0.f;
    float ssum = ev;
    ssum += __shfl_xor(ssum, 1);
    ssum += __shfl_xor(ssum, 2);
    ssum += __shfl_xor(ssum, 4);
    const float lg = logf(ssum);
    if (lane < OUTD) out[(long)r * OUTD + lane] = x - m - lg;
}

extern "C" void kernel_launch(void* const* d_in, const int* in_sizes, int n_in,
                              void* d_out, int out_size, void* d_ws, size_t ws_size,
                              hipStream_t stream)
{
    const float* feat  = (const float*)d_in[0];
    const int*   esrc  = (const int*)d_in[1];
    const int*   edst  = (const int*)d_in[2];
    const float* avals = (const float*)d_in[3];
    const float* W1    = (const float*)d_in[4];
    const float* b1    = (const float*)d_in[5];
    const float* W2    = (const float*)d_in[6];
    const float* b2    = (const float*)d_in[7];
    float* out = (float*)d_out;

    const int N = in_sizes[0] / IN_DIM;   // 150000
    const int E = in_sizes[1];            // 4800000
    const int NB = (N + 1023) / 1024;     // 147 (<=256 for scan2)

    // workspace layout
    char* p = (char*)d_ws;
    float* xw1   = (float*)p; p += (size_t)N * HID * sizeof(float);
    float* xw2   = (float*)p; p += (size_t)N * 8 * sizeof(float);
    int*   cnt   = (int*)p;   p += (size_t)N * sizeof(int);
    int*   offs  = (int*)p;   p += (size_t)(N + 1) * sizeof(int);
    int*   cursor= (int*)p;   p += (size_t)N * sizeof(int);
    int*   bsum  = (int*)p;   p += 256 * sizeof(int);
    int*   bbase = (int*)p;   p += 256 * sizeof(int);
    p = (char*)(((uintptr_t)p + 15) & ~(uintptr_t)15);
    uint2* pairs = (uint2*)p;

    hipMemsetAsync(cnt, 0, (size_t)N * sizeof(int), stream);

    gemm1_kernel<<<(N + BRW - 1) / BRW, 512, 0, stream>>>(feat, W1, xw1, N);

    hist_kernel<<<(E + 255) / 256, 256, 0, stream>>>(edst, cnt, E);
    scan1_kernel<<<NB, 256, 0, stream>>>(cnt, offs, bsum, N);
    scan2_kernel<<<1, 256, 0, stream>>>(bsum, bbase, NB);
    scan3_kernel<<<NB, 256, 0, stream>>>(offs, cursor, bbase, N, E);
    fill_kernel<<<(E + 255) / 256, 256, 0, stream>>>(esrc, edst, avals, cursor, pairs, E);

    gather1_kernel<<<(N + 3) / 4, 256, 0, stream>>>(pairs, offs, xw1, b1, W2, xw2, N);
    gather2_kernel<<<(N + 3) / 4, 256, 0, stream>>>(pairs, offs, xw2, b2, out, N);
}

// Round 7
// 1139.117 us; speedup vs baseline: 1.0885x; 1.0885x over previous
//
#include <hip/hip_runtime.h>
#include <float.h>
#include <stdint.h>

#define IN_DIM 1433
#define HID 16
#define OUTD 7

// ---------------- GEMM1: xw1[N][16] = feat[N][1433] @ W1[1433][16] -------------
// Per-thread-row streaming: thread owns one row, reads it sequentially with
// 16-B-aligned float4 loads. Row assignment row = base + 4*lane + wave makes
// (row & 3) wave-uniform, so the alignment head h and every k index are
// wave-uniform -> W1[k][:] is a scalar (s_load broadcast) operand. No LDS, no
// barriers, no DMA: ~64 distinct cache lines in flight per wave instruction,
// massively parallel line streams (the mechanism that hits ~6.5 TB/s here).
__global__ __launch_bounds__(256) void gemm1_kernel(
    const float* __restrict__ feat, const float* __restrict__ W1,
    float* __restrict__ xw1, int N)
{
    const int t = threadIdx.x;
    const int lane = t & 63;
    const int w = t >> 6;                  // wave 0..3
    const int base = blockIdx.x * 256;
    const int row = base + lane * 4 + w;   // lanes stride 4 rows -> distinct lines
    if (row >= N) return;

    // alignment class of this row's base (floats): wave-uniform since base%4==0
    const int h    = __builtin_amdgcn_readfirstlane((4 - ((base + w) & 3)) & 3);
    const int nf4  = __builtin_amdgcn_readfirstlane((IN_DIM - h) >> 2);
    const int kend = h + nf4 * 4;

    const float* __restrict__ rowp = feat + (size_t)row * IN_DIM;

    float acc[16];
#pragma unroll
    for (int j = 0; j < 16; ++j) acc[j] = 0.f;

    // head (0..3 scalar elements until 16-B alignment)
    for (int k = 0; k < h; ++k) {
        const float x = rowp[k];
        const float* wr = W1 + k * HID;
#pragma unroll
        for (int j = 0; j < 16; ++j) acc[j] += x * wr[j];
    }

    // main: aligned float4 stream over this row; k indices wave-uniform
    const float4* __restrict__ vp = (const float4*)(rowp + h);
#pragma unroll 2
    for (int c = 0; c < nf4; ++c) {
        const float4 v = vp[c];
        const float* w0 = W1 + (h + c * 4) * HID;
#pragma unroll
        for (int j = 0; j < 16; ++j) acc[j] += v.x * w0[j];
#pragma unroll
        for (int j = 0; j < 16; ++j) acc[j] += v.y * w0[HID + j];
#pragma unroll
        for (int j = 0; j < 16; ++j) acc[j] += v.z * w0[2 * HID + j];
#pragma unroll
        for (int j = 0; j < 16; ++j) acc[j] += v.w * w0[3 * HID + j];
    }

    // tail (0..3 scalar elements)
    for (int k = kend; k < IN_DIM; ++k) {
        const float x = rowp[k];
        const float* wr = W1 + k * HID;
#pragma unroll
        for (int j = 0; j < 16; ++j) acc[j] += x * wr[j];
    }

    float4* o = (float4*)(xw1 + (size_t)row * HID);
    o[0] = make_float4(acc[0],  acc[1],  acc[2],  acc[3]);
    o[1] = make_float4(acc[4],  acc[5],  acc[6],  acc[7]);
    o[2] = make_float4(acc[8],  acc[9],  acc[10], acc[11]);
    o[3] = make_float4(acc[12], acc[13], acc[14], acc[15]);
}

// ---------------- CSR build: histogram -> scan -> counting-sort fill ----------
__global__ __launch_bounds__(256) void hist_kernel(
    const int* __restrict__ dst, int* __restrict__ cnt, int E)
{
    const int e = blockIdx.x * 256 + threadIdx.x;
    if (e < E) atomicAdd(&cnt[dst[e]], 1);
}

// block = 256 threads, 4 elems/thread -> 1024 per block
__global__ __launch_bounds__(256) void scan1_kernel(
    const int* __restrict__ cnt, int* __restrict__ offs,
    int* __restrict__ bsum, int N)
{
    __shared__ int lds[256];
    const int t = threadIdx.x, b = blockIdx.x;
    const int base = b * 1024 + t * 4;
    int c0 = 0, c1 = 0, c2 = 0, c3 = 0;
    if (base + 0 < N) c0 = cnt[base + 0];
    if (base + 1 < N) c1 = cnt[base + 1];
    if (base + 2 < N) c2 = cnt[base + 2];
    if (base + 3 < N) c3 = cnt[base + 3];
    const int s = c0 + c1 + c2 + c3;
    lds[t] = s;
    __syncthreads();
    for (int off = 1; off < 256; off <<= 1) {
        int v = (t >= off) ? lds[t - off] : 0;
        __syncthreads();
        lds[t] += v;
        __syncthreads();
    }
    const int excl = lds[t] - s;
    if (t == 255) bsum[b] = lds[255];
    int run = excl;
    if (base + 0 < N) { offs[base + 0] = run; run += c0; }
    if (base + 1 < N) { offs[base + 1] = run; run += c1; }
    if (base + 2 < N) { offs[base + 2] = run; run += c2; }
    if (base + 3 < N) { offs[base + 3] = run; run += c3; }
}

// single block: exclusive scan of up to 256 block sums
__global__ __launch_bounds__(256) void scan2_kernel(
    const int* __restrict__ bsum, int* __restrict__ bbase, int NB)
{
    __shared__ int lds[256];
    const int t = threadIdx.x;
    const int v = (t < NB) ? bsum[t] : 0;
    lds[t] = v;
    __syncthreads();
    for (int off = 1; off < 256; off <<= 1) {
        int u = (t >= off) ? lds[t - off] : 0;
        __syncthreads();
        lds[t] += u;
        __syncthreads();
    }
    bbase[t] = lds[t] - v;
}

__global__ __launch_bounds__(256) void scan3_kernel(
    int* __restrict__ offs, int* __restrict__ cursor,
    const int* __restrict__ bbase, int N, int E)
{
    const int t = threadIdx.x, b = blockIdx.x;
    const int add = bbase[b];
    const int base = b * 1024 + t * 4;
#pragma unroll
    for (int i = 0; i < 4; ++i) {
        const int idx = base + i;
        if (idx < N) {
            const int v = offs[idx] + add;
            offs[idx] = v;
            cursor[idx] = v;
        }
    }
    if (b == 0 && t == 0) offs[N] = E;
}

__global__ __launch_bounds__(256) void fill_kernel(
    const int* __restrict__ src, const int* __restrict__ dst,
    const float* __restrict__ a, int* __restrict__ cursor,
    uint2* __restrict__ pairs, int E)
{
    const int e = blockIdx.x * 256 + threadIdx.x;
    if (e >= E) return;
    const int d = dst[e];
    const int pos = atomicAdd(&cursor[d], 1);
    pairs[pos] = make_uint2((unsigned)src[e], __float_as_uint(a[e]));
}

// ------- gather1: agg = sum(a*xw1[src]) ; fused h=relu(agg+b1); xw2 = h@W2 ----
// one wave per dst row: 16 lanes (dims) x 4 edge groups
__global__ __launch_bounds__(256) void gather1_kernel(
    const uint2* __restrict__ pairs, const int* __restrict__ offs,
    const float* __restrict__ xw1, const float* __restrict__ b1,
    const float* __restrict__ W2, float* __restrict__ xw2, int N)
{
    __shared__ float w2s[HID * OUTD];
    const int t = threadIdx.x;
    if (t < HID * OUTD) w2s[t] = W2[t];
    __syncthreads();
    const int lane = t & 63;
    const int r = blockIdx.x * 4 + (t >> 6);
    if (r >= N) return;
    const int dim = lane & 15;
    const int grp = lane >> 4;
    const int start = offs[r], end = offs[r + 1];
    float acc0 = 0.f, acc1 = 0.f;
    int e = start + grp;
    for (; e + 4 < end; e += 8) {
        const uint2 p0 = pairs[e];
        const uint2 p1 = pairs[e + 4];
        acc0 += __uint_as_float(p0.y) * xw1[(long)p0.x * HID + dim];
        acc1 += __uint_as_float(p1.y) * xw1[(long)p1.x * HID + dim];
    }
    if (e < end) {
        const uint2 p0 = pairs[e];
        acc0 += __uint_as_float(p0.y) * xw1[(long)p0.x * HID + dim];
    }
    float acc = acc0 + acc1;
    acc += __shfl_xor(acc, 16);
    acc += __shfl_xor(acc, 32);
    const float h = fmaxf(acc + b1[dim], 0.f);
    float sacc = 0.f;
    const int c = (dim < OUTD) ? dim : 0;
#pragma unroll
    for (int j = 0; j < HID; ++j) {
        const float hj = __shfl(h, j);
        sacc += hj * w2s[j * OUTD + c];
    }
    if (lane < 8) xw2[(long)r * 8 + lane] = (lane < OUTD) ? sacc : 0.f;
}

// ------- gather2: o = sum(a*xw2[src]) + b2 ; fused log_softmax -> out ---------
__global__ __launch_bounds__(256) void gather2_kernel(
    const uint2* __restrict__ pairs, const int* __restrict__ offs,
    const float* __restrict__ xw2, const float* __restrict__ b2,
    float* __restrict__ out, int N)
{
    const int t = threadIdx.x;
    const int lane = t & 63;
    const int r = blockIdx.x * 4 + (t >> 6);
    if (r >= N) return;
    const int dim = lane & 7;
    const int grp = lane >> 3;
    const int start = offs[r], end = offs[r + 1];
    float acc0 = 0.f, acc1 = 0.f;
    int e = start + grp;
    for (; e + 8 < end; e += 16) {
        const uint2 p0 = pairs[e];
        const uint2 p1 = pairs[e + 8];
        acc0 += __uint_as_float(p0.y) * xw2[(long)p0.x * 8 + dim];
        acc1 += __uint_as_float(p1.y) * xw2[(long)p1.x * 8 + dim];
    }
    if (e < end) {
        const uint2 p0 = pairs[e];
        acc0 += __uint_as_float(p0.y) * xw2[(long)p0.x * 8 + dim];
    }
    float acc = acc0 + acc1;
    acc += __shfl_xor(acc, 8);
    acc += __shfl_xor(acc, 16);
    acc += __shfl_xor(acc, 32);
    float x = (dim < OUTD) ? (acc + b2[dim]) : -FLT_MAX;
    float m = x;
    m = fmaxf(m, __shfl_xor(m, 1));
    m = fmaxf(m, __shfl_xor(m, 2));
    m = fmaxf(m, __shfl_xor(m, 4));
    const float ev = (dim < OUTD) ? expf(x - m) : 0.f;
    float ssum = ev;
    ssum += __shfl_xor(ssum, 1);
    ssum += __shfl_xor(ssum, 2);
    ssum += __shfl_xor(ssum, 4);
    const float lg = logf(ssum);
    if (lane < OUTD) out[(long)r * OUTD + lane] = x - m - lg;
}

extern "C" void kernel_launch(void* const* d_in, const int* in_sizes, int n_in,
                              void* d_out, int out_size, void* d_ws, size_t ws_size,
                              hipStream_t stream)
{
    const float* feat  = (const float*)d_in[0];
    const int*   esrc  = (const int*)d_in[1];
    const int*   edst  = (const int*)d_in[2];
    const float* avals = (const float*)d_in[3];
    const float* W1    = (const float*)d_in[4];
    const float* b1    = (const float*)d_in[5];
    const float* W2    = (const float*)d_in[6];
    const float* b2    = (const float*)d_in[7];
    float* out = (float*)d_out;

    const int N = in_sizes[0] / IN_DIM;   // 150000
    const int E = in_sizes[1];            // 4800000
    const int NB = (N + 1023) / 1024;     // 147 (<=256 for scan2)

    // workspace layout
    char* p = (char*)d_ws;
    float* xw1   = (float*)p; p += (size_t)N * HID * sizeof(float);
    float* xw2   = (float*)p; p += (size_t)N * 8 * sizeof(float);
    int*   cnt   = (int*)p;   p += (size_t)N * sizeof(int);
    int*   offs  = (int*)p;   p += (size_t)(N + 1) * sizeof(int);
    int*   cursor= (int*)p;   p += (size_t)N * sizeof(int);
    int*   bsum  = (int*)p;   p += 256 * sizeof(int);
    int*   bbase = (int*)p;   p += 256 * sizeof(int);
    p = (char*)(((uintptr_t)p + 15) & ~(uintptr_t)15);
    uint2* pairs = (uint2*)p;

    hipMemsetAsync(cnt, 0, (size_t)N * sizeof(int), stream);

    gemm1_kernel<<<(N + 255) / 256, 256, 0, stream>>>(feat, W1, xw1, N);

    hist_kernel<<<(E + 255) / 256, 256, 0, stream>>>(edst, cnt, E);
    scan1_kernel<<<NB, 256, 0, stream>>>(cnt, offs, bsum, N);
    scan2_kernel<<<1, 256, 0, stream>>>(bsum, bbase, NB);
    scan3_kernel<<<NB, 256, 0, stream>>>(offs, cursor, bbase, N, E);
    fill_kernel<<<(E + 255) / 256, 256, 0, stream>>>(esrc, edst, avals, cursor, pairs, E);

    gather1_kernel<<<(N + 3) / 4, 256, 0, stream>>>(pairs, offs, xw1, b1, W2, xw2, N);
    gather2_kernel<<<(N + 3) / 4, 256, 0, stream>>>(pairs, offs, xw2, b2, out, N);
}

// Round 8
// 1002.552 us; speedup vs baseline: 1.2367x; 1.1362x over previous
//
#include <hip/hip_runtime.h>
#include <float.h>
#include <stdint.h>

#define IN_DIM 1433
#define HID 16
#define OUTD 7

#define KC 32
#define GROWS 64
#define NT ((IN_DIM + KC - 1) / KC)      // 45
#define KLAST (IN_DIM - (NT - 1) * KC)   // 25

#define AS1 __attribute__((address_space(1)))
#define AS3 __attribute__((address_space(3)))

// ---------------- GEMM1: xw1[N][16] = feat[N][1433] @ W1[1433][16] -------------
// 64 rows/block, 16 KB LDS, (256,8) -> 8 blocks/CU = 32 waves/CU: block-level
// TLP hides each block's barrier drain (the convoy suspected in R2-R7).
// Wave w computes output quad q=w for all 64 rows. Stage via width-4
// global_load_lds, float4-granule XOR swizzle (both-sides, rule #21):
// physical float4-block p of row r holds global k-block p^(r&7); read of
// k-block b goes to physical b^(r&7) via ds_read_b128 -> 8 lanes per
// bank-quad = the b128 minimum (effectively conflict-free).
__global__ __launch_bounds__(256, 8) void gemm1_kernel(
    const float* __restrict__ feat, const float* __restrict__ W1,
    float* __restrict__ xw1, int N)
{
    __shared__ float xs[2][GROWS * KC];   // 2 * 8 KB
    const int t = threadIdx.x;
    const int lane = t & 63;
    const int w = t >> 6;                 // wave 0..3
    const int row0 = blockIdx.x * GROWS;
    const long maxElem = (long)N * IN_DIM - 1;

    const int r  = t & 63;                // row owned for compute
    const int rb = r & 7;                 // read-side block swizzle key
    const int q4 = __builtin_amdgcn_readfirstlane(w) * 4;  // output quad base

    float acc[4] = {0.f, 0.f, 0.f, 0.f};

    // stage one 64x32 tile: 8 width-4 DMA instrs per wave (2 rows x 32 cols each)
    auto stage = [&](int buf, int k0) {
#pragma unroll
        for (int i = 0; i < 8; ++i) {
            const int ri = (i * 4 + w) * 2 + (lane >> 5);
            const int cs = lane & 31;
            const int gcol = (cs & 3) | (((cs >> 2) ^ (ri & 7)) << 2);
            long elem = (long)(row0 + ri) * IN_DIM + k0 + gcol;
            if (elem > maxElem) elem = maxElem;   // tail clamp (unused rows)
            __builtin_amdgcn_global_load_lds(
                (const AS1 void*)(feat + elem),
                (AS3 void*)(&xs[buf][(i * 4 + w) * 64]), 4, 0, 0);
        }
    };

#define COMPUTE(buf, k0v, KMAX)                                              \
    {                                                                        \
        const float* xrow = &xs[buf][r * KC];                                \
        _Pragma("unroll")                                                    \
        for (int b = 0; b < ((KMAX) >> 2); ++b) {                            \
            const float4 xv = *(const float4*)&xrow[((b ^ rb) << 2)];        \
            const float* wk = W1 + (size_t)((k0v) + 4 * b) * HID + q4;       \
            const float4 w0 = *(const float4*)(wk);                          \
            const float4 w1 = *(const float4*)(wk + HID);                    \
            const float4 w2 = *(const float4*)(wk + 2 * HID);                \
            const float4 w3 = *(const float4*)(wk + 3 * HID);                \
            acc[0] += xv.x * w0.x; acc[1] += xv.x * w0.y;                    \
            acc[2] += xv.x * w0.z; acc[3] += xv.x * w0.w;                    \
            acc[0] += xv.y * w1.x; acc[1] += xv.y * w1.y;                    \
            acc[2] += xv.y * w1.z; acc[3] += xv.y * w1.w;                    \
            acc[0] += xv.z * w2.x; acc[1] += xv.z * w2.y;                    \
            acc[2] += xv.z * w2.z; acc[3] += xv.z * w2.w;                    \
            acc[0] += xv.w * w3.x; acc[1] += xv.w * w3.y;                    \
            acc[2] += xv.w * w3.z; acc[3] += xv.w * w3.w;                    \
        }                                                                    \
        if ((KMAX) & 3) {   /* KLAST=25: one remaining k */                  \
            const int b = (KMAX) >> 2;                                       \
            const float4 xv = *(const float4*)&xrow[((b ^ rb) << 2)];        \
            const float* wk = W1 + (size_t)((k0v) + 4 * b) * HID + q4;       \
            const float4 w0 = *(const float4*)(wk);                          \
            acc[0] += xv.x * w0.x; acc[1] += xv.x * w0.y;                    \
            acc[2] += xv.x * w0.z; acc[3] += xv.x * w0.w;                    \
        }                                                                    \
    }

    stage(0, 0);
    __syncthreads();   // tile 0 resident
    for (int it = 0; it < NT - 1; ++it) {
        stage((it & 1) ^ 1, (it + 1) * KC);   // async prefetch next tile
        COMPUTE(it & 1, it * KC, KC);         // compute current tile
        __syncthreads();                      // drain prefetch + buf reuse
    }
    COMPUTE((NT - 1) & 1, (NT - 1) * KC, KLAST);
#undef COMPUTE

    const int grow = row0 + r;
    if (grow < N)
        *(float4*)(xw1 + (size_t)grow * HID + q4) =
            make_float4(acc[0], acc[1], acc[2], acc[3]);
}

// ---------------- CSR build: histogram -> scan -> counting-sort fill ----------
__global__ __launch_bounds__(256) void hist_kernel(
    const int* __restrict__ dst, int* __restrict__ cnt, int E)
{
    const int e = blockIdx.x * 256 + threadIdx.x;
    if (e < E) atomicAdd(&cnt[dst[e]], 1);
}

__global__ __launch_bounds__(256) void scan1_kernel(
    const int* __restrict__ cnt, int* __restrict__ offs,
    int* __restrict__ bsum, int N)
{
    __shared__ int lds[256];
    const int t = threadIdx.x, b = blockIdx.x;
    const int base = b * 1024 + t * 4;
    int c0 = 0, c1 = 0, c2 = 0, c3 = 0;
    if (base + 0 < N) c0 = cnt[base + 0];
    if (base + 1 < N) c1 = cnt[base + 1];
    if (base + 2 < N) c2 = cnt[base + 2];
    if (base + 3 < N) c3 = cnt[base + 3];
    const int s = c0 + c1 + c2 + c3;
    lds[t] = s;
    __syncthreads();
    for (int off = 1; off < 256; off <<= 1) {
        int v = (t >= off) ? lds[t - off] : 0;
        __syncthreads();
        lds[t] += v;
        __syncthreads();
    }
    const int excl = lds[t] - s;
    if (t == 255) bsum[b] = lds[255];
    int run = excl;
    if (base + 0 < N) { offs[base + 0] = run; run += c0; }
    if (base + 1 < N) { offs[base + 1] = run; run += c1; }
    if (base + 2 < N) { offs[base + 2] = run; run += c2; }
    if (base + 3 < N) { offs[base + 3] = run; run += c3; }
}

__global__ __launch_bounds__(256) void scan2_kernel(
    const int* __restrict__ bsum, int* __restrict__ bbase, int NB)
{
    __shared__ int lds[256];
    const int t = threadIdx.x;
    const int v = (t < NB) ? bsum[t] : 0;
    lds[t] = v;
    __syncthreads();
    for (int off = 1; off < 256; off <<= 1) {
        int u = (t >= off) ? lds[t - off] : 0;
        __syncthreads();
        lds[t] += u;
        __syncthreads();
    }
    bbase[t] = lds[t] - v;
}

__global__ __launch_bounds__(256) void scan3_kernel(
    int* __restrict__ offs, int* __restrict__ cursor,
    const int* __restrict__ bbase, int N, int E)
{
    const int t = threadIdx.x, b = blockIdx.x;
    const int add = bbase[b];
    const int base = b * 1024 + t * 4;
#pragma unroll
    for (int i = 0; i < 4; ++i) {
        const int idx = base + i;
        if (idx < N) {
            const int v = offs[idx] + add;
            offs[idx] = v;
            cursor[idx] = v;
        }
    }
    if (b == 0 && t == 0) offs[N] = E;
}

__global__ __launch_bounds__(256) void fill_kernel(
    const int* __restrict__ src, const int* __restrict__ dst,
    const float* __restrict__ a, int* __restrict__ cursor,
    uint2* __restrict__ pairs, int E)
{
    const int e = blockIdx.x * 256 + threadIdx.x;
    if (e >= E) return;
    const int d = dst[e];
    const int pos = atomicAdd(&cursor[d], 1);
    pairs[pos] = make_uint2((unsigned)src[e], __float_as_uint(a[e]));
}

// ------- gather1: agg = sum(a*xw1[src]) ; fused h=relu(agg+b1); xw2 = h@W2 ----
// one wave per dst row, quad-major: lane = slot g (0..15) x quad c (0..3).
// Per edge: pair loaded by 4 lanes (was 16), xw1 row gathered as 4 float4s.
__global__ __launch_bounds__(256) void gather1_kernel(
    const uint2* __restrict__ pairs, const int* __restrict__ offs,
    const float* __restrict__ xw1, const float* __restrict__ b1,
    const float* __restrict__ W2, float* __restrict__ xw2, int N)
{
    __shared__ float w2s[HID * OUTD];
    const int t = threadIdx.x;
    if (t < HID * OUTD) w2s[t] = W2[t];
    __syncthreads();
    const int lane = t & 63;
    const int r = blockIdx.x * 4 + (t >> 6);
    if (r >= N) return;
    const int g = lane >> 2;
    const int c = lane & 3;
    const int start = offs[r], end = offs[r + 1];
    float4 acc = make_float4(0.f, 0.f, 0.f, 0.f);
    int e = start + g;
    for (; e + 16 < end; e += 32) {
        const uint2 p0 = pairs[e];
        const uint2 p1 = pairs[e + 16];
        const float4 v0 = *(const float4*)(xw1 + (size_t)p0.x * HID + c * 4);
        const float4 v1 = *(const float4*)(xw1 + (size_t)p1.x * HID + c * 4);
        const float a0 = __uint_as_float(p0.y);
        const float a1 = __uint_as_float(p1.y);
        acc.x += a0 * v0.x + a1 * v1.x;
        acc.y += a0 * v0.y + a1 * v1.y;
        acc.z += a0 * v0.z + a1 * v1.z;
        acc.w += a0 * v0.w + a1 * v1.w;
    }
    if (e < end) {
        const uint2 p0 = pairs[e];
        const float4 v0 = *(const float4*)(xw1 + (size_t)p0.x * HID + c * 4);
        const float a0 = __uint_as_float(p0.y);
        acc.x += a0 * v0.x; acc.y += a0 * v0.y;
        acc.z += a0 * v0.z; acc.w += a0 * v0.w;
    }
    // reduce over g (lanes 4 apart): 4 butterfly steps x 4 floats
#pragma unroll
    for (int m = 4; m < 64; m <<= 1) {
        acc.x += __shfl_xor(acc.x, m);
        acc.y += __shfl_xor(acc.y, m);
        acc.z += __shfl_xor(acc.z, m);
        acc.w += __shfl_xor(acc.w, m);
    }
    const float4 b1v = ((const float4*)b1)[c];
    float4 h;
    h.x = fmaxf(acc.x + b1v.x, 0.f);
    h.y = fmaxf(acc.y + b1v.y, 0.f);
    h.z = fmaxf(acc.z + b1v.z, 0.f);
    h.w = fmaxf(acc.w + b1v.w, 0.f);
    // gather all 16 h values (lane cc holds quad cc for cc=0..3)
    float hh[16];
#pragma unroll
    for (int cc = 0; cc < 4; ++cc) {
        hh[cc * 4 + 0] = __shfl(h.x, cc);
        hh[cc * 4 + 1] = __shfl(h.y, cc);
        hh[cc * 4 + 2] = __shfl(h.z, cc);
        hh[cc * 4 + 3] = __shfl(h.w, cc);
    }
    const int col = (lane & 7) < OUTD ? (lane & 7) : 0;
    float sacc = 0.f;
#pragma unroll
    for (int j = 0; j < HID; ++j) sacc += hh[j] * w2s[j * OUTD + col];
    if (lane < 8) xw2[(size_t)r * 8 + lane] = (lane < OUTD) ? sacc : 0.f;
}

// ------- gather2: o = sum(a*xw2[src]) + b2 ; fused log_softmax -> out ---------
// one wave per dst row: lane = slot g (0..31) x quad c (0..1).
__global__ __launch_bounds__(256) void gather2_kernel(
    const uint2* __restrict__ pairs, const int* __restrict__ offs,
    const float* __restrict__ xw2, const float* __restrict__ b2,
    float* __restrict__ out, int N)
{
    const int t = threadIdx.x;
    const int lane = t & 63;
    const int r = blockIdx.x * 4 + (t >> 6);
    if (r >= N) return;
    const int g = lane >> 1;
    const int c = lane & 1;
    const int start = offs[r], end = offs[r + 1];
    float4 acc = make_float4(0.f, 0.f, 0.f, 0.f);
    for (int e = start + g; e < end; e += 32) {
        const uint2 p = pairs[e];
        const float4 v = *(const float4*)(xw2 + (size_t)p.x * 8 + c * 4);
        const float a = __uint_as_float(p.y);
        acc.x += a * v.x; acc.y += a * v.y;
        acc.z += a * v.z; acc.w += a * v.w;
    }
#pragma unroll
    for (int m = 2; m < 64; m <<= 1) {
        acc.x += __shfl_xor(acc.x, m);
        acc.y += __shfl_xor(acc.y, m);
        acc.z += __shfl_xor(acc.z, m);
        acc.w += __shfl_xor(acc.w, m);
    }
    float4 x;
    if (c == 0) {
        const float4 b2v = *(const float4*)b2;
        x.x = acc.x + b2v.x; x.y = acc.y + b2v.y;
        x.z = acc.z + b2v.z; x.w = acc.w + b2v.w;
    } else {
        x.x = acc.x + b2[4]; x.y = acc.y + b2[5];
        x.z = acc.z + b2[6]; x.w = -FLT_MAX;
    }
    float mymax = fmaxf(fmaxf(x.x, x.y), x.z);
    if (c == 0) mymax = fmaxf(mymax, x.w);
    const float m = fmaxf(mymax, __shfl_xor(mymax, 1));
    float es = expf(x.x - m) + expf(x.y - m) + expf(x.z - m);
    if (c == 0) es += expf(x.w - m);
    const float s = es + __shfl_xor(es, 1);
    const float lg = logf(s);
    float* op = out + (size_t)r * OUTD;
    if (c == 0) {
        op[0] = x.x - m - lg; op[1] = x.y - m - lg;
        op[2] = x.z - m - lg; op[3] = x.w - m - lg;
    } else {
        op[4] = x.x - m - lg; op[5] = x.y - m - lg;
        op[6] = x.z - m - lg;
    }
}

extern "C" void kernel_launch(void* const* d_in, const int* in_sizes, int n_in,
                              void* d_out, int out_size, void* d_ws, size_t ws_size,
                              hipStream_t stream)
{
    const float* feat  = (const float*)d_in[0];
    const int*   esrc  = (const int*)d_in[1];
    const int*   edst  = (const int*)d_in[2];
    const float* avals = (const float*)d_in[3];
    const float* W1    = (const float*)d_in[4];
    const float* b1    = (const float*)d_in[5];
    const float* W2    = (const float*)d_in[6];
    const float* b2    = (const float*)d_in[7];
    float* out = (float*)d_out;

    const int N = in_sizes[0] / IN_DIM;   // 150000
    const int E = in_sizes[1];            // 4800000
    const int NB = (N + 1023) / 1024;     // 147 (<=256 for scan2)

    // workspace layout
    char* p = (char*)d_ws;
    float* xw1   = (float*)p; p += (size_t)N * HID * sizeof(float);
    float* xw2   = (float*)p; p += (size_t)N * 8 * sizeof(float);
    int*   cnt   = (int*)p;   p += (size_t)N * sizeof(int);
    int*   offs  = (int*)p;   p += (size_t)(N + 1) * sizeof(int);
    int*   cursor= (int*)p;   p += (size_t)N * sizeof(int);
    int*   bsum  = (int*)p;   p += 256 * sizeof(int);
    int*   bbase = (int*)p;   p += 256 * sizeof(int);
    p = (char*)(((uintptr_t)p + 15) & ~(uintptr_t)15);
    uint2* pairs = (uint2*)p;

    hipMemsetAsync(cnt, 0, (size_t)N * sizeof(int), stream);

    gemm1_kernel<<<(N + GROWS - 1) / GROWS, 256, 0, stream>>>(feat, W1, xw1, N);

    hist_kernel<<<(E + 255) / 256, 256, 0, stream>>>(edst, cnt, E);
    scan1_kernel<<<NB, 256, 0, stream>>>(cnt, offs, bsum, N);
    scan2_kernel<<<1, 256, 0, stream>>>(bsum, bbase, NB);
    scan3_kernel<<<NB, 256, 0, stream>>>(offs, cursor, bbase, N, E);
    fill_kernel<<<(E + 255) / 256, 256, 0, stream>>>(esrc, edst, avals, cursor, pairs, E);

    gather1_kernel<<<(N + 3) / 4, 256, 0, stream>>>(pairs, offs, xw1, b1, W2, xw2, N);
    gather2_kernel<<<(N + 3) / 4, 256, 0, stream>>>(pairs, offs, xw2, b2, out, N);
}